// Round 1
// baseline (887.904 us; speedup 1.0000x reference)
//
#include <hip/hip_runtime.h>

// ---------------- CSR construction ----------------

__global__ void deg_count_kernel(const int* __restrict__ dst, int E, int* __restrict__ deg) {
    int e = blockIdx.x * blockDim.x + threadIdx.x;
    if (e < E) atomicAdd(&deg[dst[e]], 1);
}

// Single-block exclusive scan over deg[0..n) -> offs, cursor; also dinv = rsqrt(deg+1).
__global__ void scan_kernel(const int* __restrict__ deg, int n,
                            int* __restrict__ offs, int* __restrict__ cursor,
                            float* __restrict__ dinv) {
    __shared__ int partial[1024];
    int tid = threadIdx.x;
    int chunk = (n + 1023) / 1024;
    int start = tid * chunk;
    int end = start + chunk;
    if (start > n) start = n;
    if (end > n) end = n;
    int s = 0;
    for (int i = start; i < end; ++i) s += deg[i];
    partial[tid] = s;
    __syncthreads();
    // Hillis-Steele inclusive scan
    for (int off = 1; off < 1024; off <<= 1) {
        int v = 0;
        if (tid >= off) v = partial[tid - off];
        __syncthreads();
        partial[tid] += v;
        __syncthreads();
    }
    int run = (tid == 0) ? 0 : partial[tid - 1];
    for (int i = start; i < end; ++i) {
        offs[i] = run;
        cursor[i] = run;
        run += deg[i];
        dinv[i] = rsqrtf((float)(deg[i] + 1));  // +1 self-loop; always > 0
    }
    if (tid == 0) offs[n] = partial[1023];
}

__global__ void csr_fill_kernel(const int* __restrict__ src, const int* __restrict__ dst, int E,
                                int* __restrict__ cursor, int* __restrict__ csr) {
    int e = blockIdx.x * blockDim.x + threadIdx.x;
    if (e < E) {
        int d = dst[e];
        int p = atomicAdd(&cursor[d], 1);
        csr[p] = src[e];
    }
}

// ---------------- fp32 tiled GEMM: C[M,N] = A[M,K] @ B[K,N] ----------------
// A row-major with stride lda (lets us read strided column-slices of d_out).

#define BM 128
#define BN 128
#define BK 16
#define TM 8
#define TN 8
#define AS_LD (BM + 4)

__global__ __launch_bounds__(256) void gemm_kernel(
        const float* __restrict__ A, int lda,
        const float* __restrict__ B, int ldb,
        float* __restrict__ C, int ldc,
        int M, int K) {
    __shared__ float As[BK][AS_LD];   // transposed: As[k][m]
    __shared__ float Bs[BK][BN];

    int tid = threadIdx.x;
    int bm = blockIdx.x * BM;
    int bn = blockIdx.y * BN;
    int tx = tid & 15;
    int ty = tid >> 4;

    float acc[TM][TN];
#pragma unroll
    for (int i = 0; i < TM; ++i)
#pragma unroll
        for (int j = 0; j < TN; ++j) acc[i][j] = 0.f;

    int ar = tid >> 2;          // 0..63
    int ac = (tid & 3) * 4;     // 0,4,8,12
    int brow = tid >> 5;        // 0..7
    int bcol = (tid & 31) * 4;  // 0..124

    for (int k0 = 0; k0 < K; k0 += BK) {
        // Stage A tile (128 rows x 16 cols), transposed into LDS
#pragma unroll
        for (int half = 0; half < 2; ++half) {
            int m = half * 64 + ar;
            int row = bm + m;
            float4 v = make_float4(0.f, 0.f, 0.f, 0.f);
            if (row < M) v = *(const float4*)(A + (size_t)row * lda + k0 + ac);
            As[ac + 0][m] = v.x;
            As[ac + 1][m] = v.y;
            As[ac + 2][m] = v.z;
            As[ac + 3][m] = v.w;
        }
        // Stage B tile (16 rows x 128 cols)
#pragma unroll
        for (int half = 0; half < 2; ++half) {
            int kr = half * 8 + brow;
            float4 v = *(const float4*)(B + (size_t)(k0 + kr) * ldb + bn + bcol);
            *(float4*)&Bs[kr][bcol] = v;
        }
        __syncthreads();
#pragma unroll
        for (int k = 0; k < BK; ++k) {
            float a[TM], b[TN];
            *(float4*)&a[0] = *(const float4*)&As[k][ty * TM];
            *(float4*)&a[4] = *(const float4*)&As[k][ty * TM + 4];
            *(float4*)&b[0] = *(const float4*)&Bs[k][tx * TN];
            *(float4*)&b[4] = *(const float4*)&Bs[k][tx * TN + 4];
#pragma unroll
            for (int i = 0; i < TM; ++i)
#pragma unroll
                for (int j = 0; j < TN; ++j)
                    acc[i][j] = fmaf(a[i], b[j], acc[i][j]);
        }
        __syncthreads();
    }
#pragma unroll
    for (int i = 0; i < TM; ++i) {
        int row = bm + ty * TM + i;
        if (row < M) {
            float4 v0 = make_float4(acc[i][0], acc[i][1], acc[i][2], acc[i][3]);
            float4 v1 = make_float4(acc[i][4], acc[i][5], acc[i][6], acc[i][7]);
            *(float4*)(C + (size_t)row * ldc + bn + tx * TN) = v0;
            *(float4*)(C + (size_t)row * ldc + bn + tx * TN + 4) = v1;
        }
    }
}

// ---------------- Aggregation: out[d] = relu(dinv[d]*(sum_s h[s]*dinv[s] + h[d]*dinv[d]) + b) ----------------
// One block per destination node, one thread per channel.

__global__ void agg_kernel(const float* __restrict__ h, const float* __restrict__ dinv,
                           const int* __restrict__ offs, const int* __restrict__ csr,
                           const float* __restrict__ bias, float* __restrict__ out,
                           int C, int coloff, int out_ld) {
    int d = blockIdx.x;
    int c = threadIdx.x;
    float di = dinv[d];
    int beg = offs[d], end = offs[d + 1];
    float acc = h[(size_t)d * C + c] * di;  // self-loop term (di^2 after final scale)
    for (int e = beg; e < end; ++e) {
        int s = csr[e];
        acc += h[(size_t)s * C + c] * dinv[s];
    }
    float v = fmaf(di, acc, bias[c]);
    out[(size_t)d * out_ld + coloff + c] = fmaxf(v, 0.f);
}

// ---------------- launch ----------------

extern "C" void kernel_launch(void* const* d_in, const int* in_sizes, int n_in,
                              void* d_out, int out_size, void* d_ws, size_t ws_size,
                              hipStream_t stream) {
    const float* x  = (const float*)d_in[0];
    const int*   ei = (const int*)d_in[1];
    const float* W1 = (const float*)d_in[2];
    const float* b1 = (const float*)d_in[3];
    const float* W2 = (const float*)d_in[4];
    const float* b2 = (const float*)d_in[5];
    const float* W3 = (const float*)d_in[6];
    const float* b3 = (const float*)d_in[7];

    const int IN_C = 256, H2 = 256, H1 = 128, OUT_C = 128;
    const int OUT_LD = H2 + H1 + OUT_C;  // 512
    int n = in_sizes[0] / IN_C;          // 50000
    int E = in_sizes[1] / 2;             // 800000
    const int* src = ei;
    const int* dst = ei + E;

    // workspace carve (256B-aligned chunks)
    char* ws = (char*)d_ws;
    int* deg    = (int*)ws;    ws += ((size_t)n * 4 + 255) & ~(size_t)255;
    int* offs   = (int*)ws;    ws += (((size_t)n + 1) * 4 + 255) & ~(size_t)255;
    int* cursor = (int*)ws;    ws += ((size_t)n * 4 + 255) & ~(size_t)255;
    float* dinv = (float*)ws;  ws += ((size_t)n * 4 + 255) & ~(size_t)255;
    int* csr    = (int*)ws;    ws += ((size_t)E * 4 + 255) & ~(size_t)255;
    float* t    = (float*)ws;  // n * 256 floats (reused per layer)

    float* out = (float*)d_out;

    hipMemsetAsync(deg, 0, (size_t)n * sizeof(int), stream);
    deg_count_kernel<<<(E + 255) / 256, 256, 0, stream>>>(dst, E, deg);
    scan_kernel<<<1, 1024, 0, stream>>>(deg, n, offs, cursor, dinv);
    csr_fill_kernel<<<(E + 255) / 256, 256, 0, stream>>>(src, dst, E, cursor, csr);

    // Layer 1: t = x @ W1 ; agg -> out[:, 0:256]
    gemm_kernel<<<dim3((n + BM - 1) / BM, H2 / BN), 256, 0, stream>>>(x, IN_C, W1, H2, t, H2, n, IN_C);
    agg_kernel<<<n, H2, 0, stream>>>(t, dinv, offs, csr, b1, out, H2, 0, OUT_LD);

    // Layer 2: t = h1 @ W2 ; agg -> out[:, 256:384]
    gemm_kernel<<<dim3((n + BM - 1) / BM, H1 / BN), 256, 0, stream>>>(out, OUT_LD, W2, H1, t, H1, n, H2);
    agg_kernel<<<n, H1, 0, stream>>>(t, dinv, offs, csr, b2, out, H1, H2, OUT_LD);

    // Layer 3: t = h2 @ W3 ; agg -> out[:, 384:512]
    gemm_kernel<<<dim3((n + BM - 1) / BM, OUT_C / BN), 256, 0, stream>>>(out + H2, OUT_LD, W3, OUT_C, t, OUT_C, n, H1);
    agg_kernel<<<n, OUT_C, 0, stream>>>(t, dinv, offs, csr, b3, out, OUT_C, H2 + H1, OUT_LD);
}

// Round 2
// 555.139 us; speedup vs baseline: 1.5994x; 1.5994x over previous
//
#include <hip/hip_runtime.h>

typedef __attribute__((ext_vector_type(8))) short bfrag8;   // 8 bf16 = 4 VGPRs
typedef __attribute__((ext_vector_type(4))) float f32x4v;   // MFMA acc

__device__ inline short f2bf(float f) {
    unsigned u = __builtin_bit_cast(unsigned, f);
    u = (u + 0x7FFFu + ((u >> 16) & 1u)) >> 16;
    return (short)u;
}
__device__ inline float bf2f(short s) {
    unsigned u = ((unsigned)(unsigned short)s) << 16;
    return __builtin_bit_cast(float, u);
}
__device__ inline int pack2(short lo, short hi) {
    return (int)(((unsigned)(unsigned short)lo) | (((unsigned)(unsigned short)hi) << 16));
}

// ---------------- CSR construction ----------------

__global__ void deg_count_kernel(const int* __restrict__ dst, int E, int* __restrict__ deg) {
    int e = blockIdx.x * blockDim.x + threadIdx.x;
    if (e < E) atomicAdd(&deg[dst[e]], 1);
}

__global__ void scan_kernel(const int* __restrict__ deg, int n,
                            int* __restrict__ offs, int* __restrict__ cursor,
                            float* __restrict__ dinv) {
    __shared__ int partial[1024];
    int tid = threadIdx.x;
    int chunk = (n + 1023) / 1024;
    int start = tid * chunk, end = start + chunk;
    if (start > n) start = n;
    if (end > n) end = n;
    int s = 0;
    for (int i = start; i < end; ++i) s += deg[i];
    partial[tid] = s;
    __syncthreads();
    for (int off = 1; off < 1024; off <<= 1) {
        int v = 0;
        if (tid >= off) v = partial[tid - off];
        __syncthreads();
        partial[tid] += v;
        __syncthreads();
    }
    int run = (tid == 0) ? 0 : partial[tid - 1];
    for (int i = start; i < end; ++i) {
        offs[i] = run;
        cursor[i] = run;
        run += deg[i];
        dinv[i] = rsqrtf((float)(deg[i] + 1));
    }
    if (tid == 0) offs[n] = partial[1023];
}

__global__ void csr_fill_kernel(const int* __restrict__ src, const int* __restrict__ dst, int E,
                                int* __restrict__ cursor, int* __restrict__ csr) {
    int e = blockIdx.x * blockDim.x + threadIdx.x;
    if (e < E) {
        int d = dst[e];
        int p = atomicAdd(&cursor[d], 1);
        csr[p] = src[e];
    }
}

// ---------------- weight transpose + bf16 convert: Wt[n][k] = bf16(W[k][n]) ----------------

__global__ void wt_kernel(const float* __restrict__ W, short* __restrict__ Wt,
                          int K, int logN) {
    int i = blockIdx.x * blockDim.x + threadIdx.x;
    int total = K << logN;
    if (i < total) {
        int k = i >> logN;
        int n = i & ((1 << logN) - 1);
        Wt[(size_t)n * K + k] = f2bf(W[i]);
    }
}

// ---------------- bf16 MFMA GEMM: Tout[m][n] = bf16( (A[m,:] @ B[:,n]) * dinv[m] ) ----------------
// A: fp32 row-major, stride lda. Bt: bf16 [N][K]. Tile 128x128, BK=32, 4 waves (2x2 of 64x64).

#define ALD 40  // padded k-stride (bf16 elems); 80 B rows -> 16B aligned

__global__ __launch_bounds__(256) void gemm_mfma_kernel(
        const float* __restrict__ A, int lda,
        const short* __restrict__ Bt, int K,
        const float* __restrict__ dinv,
        short* __restrict__ Tout, int ldt,
        int M) {
    __shared__ short As[128][ALD];
    __shared__ short Bs[128][ALD];

    const int tid = threadIdx.x;
    const int lane = tid & 63;
    const int wid = tid >> 6;
    const int l15 = lane & 15;
    const int quad = lane >> 4;           // 0..3
    const int q8 = quad * 8;
    const int bm = blockIdx.x * 128;
    const int bn = blockIdx.y * 128;
    const int wm = (wid & 1) * 64;
    const int wn = (wid >> 1) * 64;

    f32x4v acc[4][4];
#pragma unroll
    for (int i = 0; i < 4; ++i)
#pragma unroll
        for (int j = 0; j < 4; ++j) acc[i][j] = (f32x4v){0.f, 0.f, 0.f, 0.f};

    const int srow = tid >> 1;            // 0..127
    const int sseg = (tid & 1) * 16;      // k offset 0/16

    for (int k0 = 0; k0 < K; k0 += 32) {
        // ---- stage A (fp32 -> bf16) ----
        {
            int grow = bm + srow;
            float4 v0 = {0,0,0,0}, v1 = {0,0,0,0}, v2 = {0,0,0,0}, v3 = {0,0,0,0};
            if (grow < M) {
                const float* p = A + (size_t)grow * lda + k0 + sseg;
                v0 = *(const float4*)(p + 0);
                v1 = *(const float4*)(p + 4);
                v2 = *(const float4*)(p + 8);
                v3 = *(const float4*)(p + 12);
            }
            int4 w0 = make_int4(pack2(f2bf(v0.x), f2bf(v0.y)), pack2(f2bf(v0.z), f2bf(v0.w)),
                                pack2(f2bf(v1.x), f2bf(v1.y)), pack2(f2bf(v1.z), f2bf(v1.w)));
            int4 w1 = make_int4(pack2(f2bf(v2.x), f2bf(v2.y)), pack2(f2bf(v2.z), f2bf(v2.w)),
                                pack2(f2bf(v3.x), f2bf(v3.y)), pack2(f2bf(v3.z), f2bf(v3.w)));
            *(int4*)&As[srow][sseg] = w0;
            *(int4*)&As[srow][sseg + 8] = w1;
        }
        // ---- stage B (bf16 copy) ----
        {
            const short* p = Bt + (size_t)(bn + srow) * K + k0 + sseg;
            int4 w0 = *(const int4*)p;
            int4 w1 = *(const int4*)(p + 8);
            *(int4*)&Bs[srow][sseg] = w0;
            *(int4*)&Bs[srow][sseg + 8] = w1;
        }
        __syncthreads();

        bfrag8 af[4], bfv[4];
#pragma unroll
        for (int mt = 0; mt < 4; ++mt)
            af[mt] = *(const bfrag8*)&As[wm + mt * 16 + l15][q8];
#pragma unroll
        for (int nt = 0; nt < 4; ++nt)
            bfv[nt] = *(const bfrag8*)&Bs[wn + nt * 16 + l15][q8];
#pragma unroll
        for (int mt = 0; mt < 4; ++mt)
#pragma unroll
            for (int nt = 0; nt < 4; ++nt)
                acc[mt][nt] = __builtin_amdgcn_mfma_f32_16x16x32_bf16(af[mt], bfv[nt], acc[mt][nt], 0, 0, 0);
        __syncthreads();
    }

    // ---- epilogue: scale by dinv[row], cvt bf16, store ----
#pragma unroll
    for (int mt = 0; mt < 4; ++mt) {
#pragma unroll
        for (int r = 0; r < 4; ++r) {
            int grow = bm + wm + mt * 16 + quad * 4 + r;
            if (grow < M) {
                float di = dinv[grow];
                short* outp = Tout + (size_t)grow * ldt + bn + wn + l15;
#pragma unroll
                for (int nt = 0; nt < 4; ++nt)
                    outp[nt * 16] = f2bf(acc[mt][nt][r] * di);
            }
        }
    }
}

// ---------------- Aggregation: out[d] = relu(dinv[d] * (sum_{s in N(d)} hn[s] + hn[d]) + b) ----------------
// hn = (x@W)*dinv[row] in bf16. One wave per dst node, 4 waves/block.

template<int C>
__global__ __launch_bounds__(256) void agg_kernel(
        const short* __restrict__ hn, const float* __restrict__ dinv,
        const int* __restrict__ offs, const int* __restrict__ csr,
        const float* __restrict__ bias, float* __restrict__ out,
        int coloff, int n) {
    constexpr int V = C / 64;  // bf16 per lane: 4 (C=256) or 2 (C=128)
    int node = blockIdx.x * 4 + (threadIdx.x >> 6);
    if (node >= n) return;
    int lane = threadIdx.x & 63;
    const short* base = hn + lane * V;

    float acc[V];
#pragma unroll
    for (int v = 0; v < V; ++v) acc[v] = 0.f;

    int beg = offs[node], end = offs[node + 1];
    int e = beg;
    if (V == 4) {
        for (; e + 4 <= end; e += 4) {
            int s0 = csr[e], s1 = csr[e + 1], s2 = csr[e + 2], s3 = csr[e + 3];
            short4 a = *(const short4*)(base + (size_t)s0 * C);
            short4 b = *(const short4*)(base + (size_t)s1 * C);
            short4 c = *(const short4*)(base + (size_t)s2 * C);
            short4 d = *(const short4*)(base + (size_t)s3 * C);
            acc[0] += bf2f(a.x) + bf2f(b.x) + bf2f(c.x) + bf2f(d.x);
            acc[1] += bf2f(a.y) + bf2f(b.y) + bf2f(c.y) + bf2f(d.y);
            acc[2] += bf2f(a.z) + bf2f(b.z) + bf2f(c.z) + bf2f(d.z);
            acc[3] += bf2f(a.w) + bf2f(b.w) + bf2f(c.w) + bf2f(d.w);
        }
        for (; e < end; ++e) {
            short4 a = *(const short4*)(base + (size_t)csr[e] * C);
            acc[0] += bf2f(a.x); acc[1] += bf2f(a.y); acc[2] += bf2f(a.z); acc[3] += bf2f(a.w);
        }
        short4 a = *(const short4*)(base + (size_t)node * C);  // self loop
        acc[0] += bf2f(a.x); acc[1] += bf2f(a.y); acc[2] += bf2f(a.z); acc[3] += bf2f(a.w);
    } else {
        for (; e + 4 <= end; e += 4) {
            int s0 = csr[e], s1 = csr[e + 1], s2 = csr[e + 2], s3 = csr[e + 3];
            short2 a = *(const short2*)(base + (size_t)s0 * C);
            short2 b = *(const short2*)(base + (size_t)s1 * C);
            short2 c = *(const short2*)(base + (size_t)s2 * C);
            short2 d = *(const short2*)(base + (size_t)s3 * C);
            acc[0] += bf2f(a.x) + bf2f(b.x) + bf2f(c.x) + bf2f(d.x);
            acc[1] += bf2f(a.y) + bf2f(b.y) + bf2f(c.y) + bf2f(d.y);
        }
        for (; e < end; ++e) {
            short2 a = *(const short2*)(base + (size_t)csr[e] * C);
            acc[0] += bf2f(a.x); acc[1] += bf2f(a.y);
        }
        short2 a = *(const short2*)(base + (size_t)node * C);
        acc[0] += bf2f(a.x); acc[1] += bf2f(a.y);
    }

    float di = dinv[node];
    float* op = out + (size_t)node * 512 + coloff + lane * V;
    if (V == 4) {
        float4 o;
        o.x = fmaxf(fmaf(di, acc[0], bias[lane * 4 + 0]), 0.f);
        o.y = fmaxf(fmaf(di, acc[1], bias[lane * 4 + 1]), 0.f);
        o.z = fmaxf(fmaf(di, acc[2], bias[lane * 4 + 2]), 0.f);
        o.w = fmaxf(fmaf(di, acc[3], bias[lane * 4 + 3]), 0.f);
        *(float4*)op = o;
    } else {
        float2 o;
        o.x = fmaxf(fmaf(di, acc[0], bias[lane * 2 + 0]), 0.f);
        o.y = fmaxf(fmaf(di, acc[1], bias[lane * 2 + 1]), 0.f);
        *(float2*)op = o;
    }
}

// ---------------- launch ----------------

extern "C" void kernel_launch(void* const* d_in, const int* in_sizes, int n_in,
                              void* d_out, int out_size, void* d_ws, size_t ws_size,
                              hipStream_t stream) {
    const float* x  = (const float*)d_in[0];
    const int*   ei = (const int*)d_in[1];
    const float* W1 = (const float*)d_in[2];
    const float* b1 = (const float*)d_in[3];
    const float* W2 = (const float*)d_in[4];
    const float* b2 = (const float*)d_in[5];
    const float* W3 = (const float*)d_in[6];
    const float* b3 = (const float*)d_in[7];

    const int IN_C = 256, H2 = 256, H1 = 128, OUT_C = 128;
    int n = in_sizes[0] / IN_C;   // 50000
    int E = in_sizes[1] / 2;      // 800000
    const int* src = ei;
    const int* dst = ei + E;

    char* ws = (char*)d_ws;
    auto carve = [&](size_t bytes) { char* p = ws; ws += (bytes + 255) & ~(size_t)255; return p; };
    int*   deg    = (int*)  carve((size_t)n * 4);
    int*   offs   = (int*)  carve(((size_t)n + 1) * 4);
    int*   cursor = (int*)  carve((size_t)n * 4);
    float* dinv   = (float*)carve((size_t)n * 4);
    int*   csr    = (int*)  carve((size_t)E * 4);
    short* Wt1    = (short*)carve((size_t)IN_C * H2 * 2);
    short* Wt2    = (short*)carve((size_t)H2 * H1 * 2);
    short* Wt3    = (short*)carve((size_t)H1 * OUT_C * 2);
    short* t      = (short*)carve((size_t)n * 256 * 2);

    float* out = (float*)d_out;

    hipMemsetAsync(deg, 0, (size_t)n * sizeof(int), stream);
    deg_count_kernel<<<(E + 255) / 256, 256, 0, stream>>>(dst, E, deg);
    scan_kernel<<<1, 1024, 0, stream>>>(deg, n, offs, cursor, dinv);
    csr_fill_kernel<<<(E + 255) / 256, 256, 0, stream>>>(src, dst, E, cursor, csr);

    wt_kernel<<<(IN_C * H2 + 255) / 256, 256, 0, stream>>>(W1, Wt1, IN_C, 8);
    wt_kernel<<<(H2 * H1 + 255) / 256, 256, 0, stream>>>(W2, Wt2, H2, 7);
    wt_kernel<<<(H1 * OUT_C + 255) / 256, 256, 0, stream>>>(W3, Wt3, H1, 7);

    int mb = (n + 127) / 128;

    // Layer 1: t = bf16((x@W1)*dinv) ; agg -> out[:,0:256]
    gemm_mfma_kernel<<<dim3(mb, H2 / 128), 256, 0, stream>>>(x, IN_C, Wt1, IN_C, dinv, t, H2, n);
    agg_kernel<256><<<(n + 3) / 4, 256, 0, stream>>>(t, dinv, offs, csr, b1, out, 0, n);

    // Layer 2: t = bf16((h1@W2)*dinv) ; agg -> out[:,256:384]
    gemm_mfma_kernel<<<dim3(mb, H1 / 128), 256, 0, stream>>>(out, 512, Wt2, H2, dinv, t, H1, n);
    agg_kernel<128><<<(n + 3) / 4, 256, 0, stream>>>(t, dinv, offs, csr, b2, out, H2, n);

    // Layer 3: t = bf16((h2@W3)*dinv) ; agg -> out[:,384:512]
    gemm_mfma_kernel<<<dim3(mb, OUT_C / 128), 256, 0, stream>>>(out + H2, 512, Wt3, H1, dinv, t, OUT_C, n);
    agg_kernel<128><<<(n + 3) / 4, 256, 0, stream>>>(t, dinv, offs, csr, b3, out, H2 + H1, n);
}

// Round 3
// 431.476 us; speedup vs baseline: 2.0578x; 1.2866x over previous
//
#include <hip/hip_runtime.h>

typedef __attribute__((ext_vector_type(8))) short bfrag8;   // 8 bf16 = 4 VGPRs
typedef __attribute__((ext_vector_type(4))) float f32x4v;   // MFMA acc

__device__ inline short f2bf(float f) {
    unsigned u = __builtin_bit_cast(unsigned, f);
    u = (u + 0x7FFFu + ((u >> 16) & 1u)) >> 16;
    return (short)u;
}
__device__ inline float bf2f(short s) {
    unsigned u = ((unsigned)(unsigned short)s) << 16;
    return __builtin_bit_cast(float, u);
}
__device__ inline int pack2(short lo, short hi) {
    return (int)(((unsigned)(unsigned short)lo) | (((unsigned)(unsigned short)hi) << 16));
}

// ---------------- CSR construction ----------------

__global__ void deg_count_kernel(const int* __restrict__ dst, int E, int* __restrict__ deg) {
    int e = blockIdx.x * blockDim.x + threadIdx.x;
    if (e < E) atomicAdd(&deg[dst[e]], 1);
}

// Phase 1: per-block (256-elem chunk) sums of deg.
__global__ void block_sum_kernel(const int* __restrict__ deg, int n, int* __restrict__ bsums) {
    int i = blockIdx.x * 256 + threadIdx.x;
    int v = (i < n) ? deg[i] : 0;
#pragma unroll
    for (int off = 32; off > 0; off >>= 1) v += __shfl_down(v, off);
    __shared__ int wsum[4];
    int lane = threadIdx.x & 63, w = threadIdx.x >> 6;
    if (lane == 0) wsum[w] = v;
    __syncthreads();
    if (threadIdx.x == 0) bsums[blockIdx.x] = wsum[0] + wsum[1] + wsum[2] + wsum[3];
}

// Phase 2: exclusive scan of block sums (B <= 256), writes offs[n] = total.
__global__ void scan_bsums_kernel(int* __restrict__ bsums, int B, int* __restrict__ offs, int n) {
    __shared__ int s[256];
    int tid = threadIdx.x;
    int v = (tid < B) ? bsums[tid] : 0;
    s[tid] = v;
    __syncthreads();
    for (int off = 1; off < 256; off <<= 1) {
        int t = (tid >= off) ? s[tid - off] : 0;
        __syncthreads();
        s[tid] += t;
        __syncthreads();
    }
    if (tid < B) bsums[tid] = (tid == 0) ? 0 : s[tid - 1];
    if (tid == 0) offs[n] = s[255];
}

// Phase 3: in-block exclusive scan + block offset -> offs/cursor; also dinv.
__global__ void scan_final_kernel(const int* __restrict__ deg, int n,
                                  const int* __restrict__ bsums,
                                  int* __restrict__ offs, int* __restrict__ cursor,
                                  float* __restrict__ dinv) {
    __shared__ int s[256];
    int tid = threadIdx.x;
    int i = blockIdx.x * 256 + tid;
    int v = (i < n) ? deg[i] : 0;
    s[tid] = v;
    __syncthreads();
    for (int off = 1; off < 256; off <<= 1) {
        int t = (tid >= off) ? s[tid - off] : 0;
        __syncthreads();
        s[tid] += t;
        __syncthreads();
    }
    if (i < n) {
        int excl = s[tid] - v + bsums[blockIdx.x];
        offs[i] = excl;
        cursor[i] = excl;
        dinv[i] = rsqrtf((float)(v + 1));
    }
}

__global__ void csr_fill_kernel(const int* __restrict__ src, const int* __restrict__ dst, int E,
                                int* __restrict__ cursor, int* __restrict__ csr) {
    int e = blockIdx.x * blockDim.x + threadIdx.x;
    if (e < E) {
        int d = dst[e];
        int p = atomicAdd(&cursor[d], 1);
        csr[p] = src[e];
    }
}

// ---------------- weight transpose + bf16 convert: Wt[n][k] = bf16(W[k][n]) ----------------

__global__ void wt_kernel(const float* __restrict__ W, short* __restrict__ Wt,
                          int K, int logN) {
    int i = blockIdx.x * blockDim.x + threadIdx.x;
    int total = K << logN;
    if (i < total) {
        int k = i >> logN;
        int n = i & ((1 << logN) - 1);
        Wt[(size_t)n * K + k] = f2bf(W[i]);
    }
}

// ---------------- bf16 MFMA GEMM: Tout[m][n] = bf16( (A[m,:] @ B[:,n]) * dinv[m] ) ----------------
// A: fp32 row-major, stride lda. Bt: bf16 [N][K]. Tile 128x128, BK=32, 4 waves (2x2 of 64x64).

#define ALD 40  // padded k-stride (bf16 elems); 80 B rows -> 16B aligned

__global__ __launch_bounds__(256) void gemm_mfma_kernel(
        const float* __restrict__ A, int lda,
        const short* __restrict__ Bt, int K,
        const float* __restrict__ dinv,
        short* __restrict__ Tout, int ldt,
        int M) {
    __shared__ short As[128][ALD];
    __shared__ short Bs[128][ALD];

    const int tid = threadIdx.x;
    const int lane = tid & 63;
    const int wid = tid >> 6;
    const int l15 = lane & 15;
    const int quad = lane >> 4;           // 0..3
    const int q8 = quad * 8;
    const int bm = blockIdx.x * 128;
    const int bn = blockIdx.y * 128;
    const int wm = (wid & 1) * 64;
    const int wn = (wid >> 1) * 64;

    f32x4v acc[4][4];
#pragma unroll
    for (int i = 0; i < 4; ++i)
#pragma unroll
        for (int j = 0; j < 4; ++j) acc[i][j] = (f32x4v){0.f, 0.f, 0.f, 0.f};

    const int srow = tid >> 1;            // 0..127
    const int sseg = (tid & 1) * 16;      // k offset 0/16

    for (int k0 = 0; k0 < K; k0 += 32) {
        // ---- stage A (fp32 -> bf16) ----
        {
            int grow = bm + srow;
            float4 v0 = {0,0,0,0}, v1 = {0,0,0,0}, v2 = {0,0,0,0}, v3 = {0,0,0,0};
            if (grow < M) {
                const float* p = A + (size_t)grow * lda + k0 + sseg;
                v0 = *(const float4*)(p + 0);
                v1 = *(const float4*)(p + 4);
                v2 = *(const float4*)(p + 8);
                v3 = *(const float4*)(p + 12);
            }
            int4 w0 = make_int4(pack2(f2bf(v0.x), f2bf(v0.y)), pack2(f2bf(v0.z), f2bf(v0.w)),
                                pack2(f2bf(v1.x), f2bf(v1.y)), pack2(f2bf(v1.z), f2bf(v1.w)));
            int4 w1 = make_int4(pack2(f2bf(v2.x), f2bf(v2.y)), pack2(f2bf(v2.z), f2bf(v2.w)),
                                pack2(f2bf(v3.x), f2bf(v3.y)), pack2(f2bf(v3.z), f2bf(v3.w)));
            *(int4*)&As[srow][sseg] = w0;
            *(int4*)&As[srow][sseg + 8] = w1;
        }
        // ---- stage B (bf16 copy) ----
        {
            const short* p = Bt + (size_t)(bn + srow) * K + k0 + sseg;
            int4 w0 = *(const int4*)p;
            int4 w1 = *(const int4*)(p + 8);
            *(int4*)&Bs[srow][sseg] = w0;
            *(int4*)&Bs[srow][sseg + 8] = w1;
        }
        __syncthreads();

        bfrag8 af[4], bfv[4];
#pragma unroll
        for (int mt = 0; mt < 4; ++mt)
            af[mt] = *(const bfrag8*)&As[wm + mt * 16 + l15][q8];
#pragma unroll
        for (int nt = 0; nt < 4; ++nt)
            bfv[nt] = *(const bfrag8*)&Bs[wn + nt * 16 + l15][q8];
#pragma unroll
        for (int mt = 0; mt < 4; ++mt)
#pragma unroll
            for (int nt = 0; nt < 4; ++nt)
                acc[mt][nt] = __builtin_amdgcn_mfma_f32_16x16x32_bf16(af[mt], bfv[nt], acc[mt][nt], 0, 0, 0);
        __syncthreads();
    }

    // ---- epilogue: scale by dinv[row], cvt bf16, store ----
#pragma unroll
    for (int mt = 0; mt < 4; ++mt) {
#pragma unroll
        for (int r = 0; r < 4; ++r) {
            int grow = bm + wm + mt * 16 + quad * 4 + r;
            if (grow < M) {
                float di = dinv[grow];
                short* outp = Tout + (size_t)grow * ldt + bn + wn + l15;
#pragma unroll
                for (int nt = 0; nt < 4; ++nt)
                    outp[nt * 16] = f2bf(acc[mt][nt][r] * di);
            }
        }
    }
}

// ---------------- Aggregation: out[d] = relu(dinv[d] * (sum_{s in N(d)} hn[s] + hn[d]) + b) ----------------
// hn = (x@W)*dinv[row] in bf16. One wave per dst node, 4 waves/block.

template<int C>
__global__ __launch_bounds__(256) void agg_kernel(
        const short* __restrict__ hn, const float* __restrict__ dinv,
        const int* __restrict__ offs, const int* __restrict__ csr,
        const float* __restrict__ bias, float* __restrict__ out,
        int coloff, int n) {
    constexpr int V = C / 64;  // bf16 per lane: 4 (C=256) or 2 (C=128)
    int node = blockIdx.x * 4 + (threadIdx.x >> 6);
    if (node >= n) return;
    int lane = threadIdx.x & 63;
    const short* base = hn + lane * V;

    float acc[V];
#pragma unroll
    for (int v = 0; v < V; ++v) acc[v] = 0.f;

    int beg = offs[node], end = offs[node + 1];
    int e = beg;
    if (V == 4) {
        for (; e + 4 <= end; e += 4) {
            int s0 = csr[e], s1 = csr[e + 1], s2 = csr[e + 2], s3 = csr[e + 3];
            short4 a = *(const short4*)(base + (size_t)s0 * C);
            short4 b = *(const short4*)(base + (size_t)s1 * C);
            short4 c = *(const short4*)(base + (size_t)s2 * C);
            short4 d = *(const short4*)(base + (size_t)s3 * C);
            acc[0] += bf2f(a.x) + bf2f(b.x) + bf2f(c.x) + bf2f(d.x);
            acc[1] += bf2f(a.y) + bf2f(b.y) + bf2f(c.y) + bf2f(d.y);
            acc[2] += bf2f(a.z) + bf2f(b.z) + bf2f(c.z) + bf2f(d.z);
            acc[3] += bf2f(a.w) + bf2f(b.w) + bf2f(c.w) + bf2f(d.w);
        }
        for (; e < end; ++e) {
            short4 a = *(const short4*)(base + (size_t)csr[e] * C);
            acc[0] += bf2f(a.x); acc[1] += bf2f(a.y); acc[2] += bf2f(a.z); acc[3] += bf2f(a.w);
        }
        short4 a = *(const short4*)(base + (size_t)node * C);  // self loop
        acc[0] += bf2f(a.x); acc[1] += bf2f(a.y); acc[2] += bf2f(a.z); acc[3] += bf2f(a.w);
    } else {
        for (; e + 4 <= end; e += 4) {
            int s0 = csr[e], s1 = csr[e + 1], s2 = csr[e + 2], s3 = csr[e + 3];
            short2 a = *(const short2*)(base + (size_t)s0 * C);
            short2 b = *(const short2*)(base + (size_t)s1 * C);
            short2 c = *(const short2*)(base + (size_t)s2 * C);
            short2 d = *(const short2*)(base + (size_t)s3 * C);
            acc[0] += bf2f(a.x) + bf2f(b.x) + bf2f(c.x) + bf2f(d.x);
            acc[1] += bf2f(a.y) + bf2f(b.y) + bf2f(c.y) + bf2f(d.y);
        }
        for (; e < end; ++e) {
            short2 a = *(const short2*)(base + (size_t)csr[e] * C);
            acc[0] += bf2f(a.x); acc[1] += bf2f(a.y);
        }
        short2 a = *(const short2*)(base + (size_t)node * C);
        acc[0] += bf2f(a.x); acc[1] += bf2f(a.y);
    }

    float di = dinv[node];
    float* op = out + (size_t)node * 512 + coloff + lane * V;
    if (V == 4) {
        float4 o;
        o.x = fmaxf(fmaf(di, acc[0], bias[lane * 4 + 0]), 0.f);
        o.y = fmaxf(fmaf(di, acc[1], bias[lane * 4 + 1]), 0.f);
        o.z = fmaxf(fmaf(di, acc[2], bias[lane * 4 + 2]), 0.f);
        o.w = fmaxf(fmaf(di, acc[3], bias[lane * 4 + 3]), 0.f);
        *(float4*)op = o;
    } else {
        float2 o;
        o.x = fmaxf(fmaf(di, acc[0], bias[lane * 2 + 0]), 0.f);
        o.y = fmaxf(fmaf(di, acc[1], bias[lane * 2 + 1]), 0.f);
        *(float2*)op = o;
    }
}

// ---------------- launch ----------------

extern "C" void kernel_launch(void* const* d_in, const int* in_sizes, int n_in,
                              void* d_out, int out_size, void* d_ws, size_t ws_size,
                              hipStream_t stream) {
    const float* x  = (const float*)d_in[0];
    const int*   ei = (const int*)d_in[1];
    const float* W1 = (const float*)d_in[2];
    const float* b1 = (const float*)d_in[3];
    const float* W2 = (const float*)d_in[4];
    const float* b2 = (const float*)d_in[5];
    const float* W3 = (const float*)d_in[6];
    const float* b3 = (const float*)d_in[7];

    const int IN_C = 256, H2 = 256, H1 = 128, OUT_C = 128;
    int n = in_sizes[0] / IN_C;   // 50000
    int E = in_sizes[1] / 2;      // 800000
    const int* src = ei;
    const int* dst = ei + E;

    char* ws = (char*)d_ws;
    auto carve = [&](size_t bytes) { char* p = ws; ws += (bytes + 255) & ~(size_t)255; return p; };
    int*   deg    = (int*)  carve((size_t)n * 4);
    int*   offs   = (int*)  carve(((size_t)n + 1) * 4);
    int*   cursor = (int*)  carve((size_t)n * 4);
    float* dinv   = (float*)carve((size_t)n * 4);
    int*   csr    = (int*)  carve((size_t)E * 4);
    int*   bsums  = (int*)  carve(256 * 4);
    short* Wt1    = (short*)carve((size_t)IN_C * H2 * 2);
    short* Wt2    = (short*)carve((size_t)H2 * H1 * 2);
    short* Wt3    = (short*)carve((size_t)H1 * OUT_C * 2);
    short* t      = (short*)carve((size_t)n * 256 * 2);

    float* out = (float*)d_out;

    int nblk = (n + 255) / 256;  // 196 <= 256

    hipMemsetAsync(deg, 0, (size_t)n * sizeof(int), stream);
    deg_count_kernel<<<(E + 255) / 256, 256, 0, stream>>>(dst, E, deg);
    block_sum_kernel<<<nblk, 256, 0, stream>>>(deg, n, bsums);
    scan_bsums_kernel<<<1, 256, 0, stream>>>(bsums, nblk, offs, n);
    scan_final_kernel<<<nblk, 256, 0, stream>>>(deg, n, bsums, offs, cursor, dinv);
    csr_fill_kernel<<<(E + 255) / 256, 256, 0, stream>>>(src, dst, E, cursor, csr);

    wt_kernel<<<(IN_C * H2 + 255) / 256, 256, 0, stream>>>(W1, Wt1, IN_C, 8);
    wt_kernel<<<(H2 * H1 + 255) / 256, 256, 0, stream>>>(W2, Wt2, H2, 7);
    wt_kernel<<<(H1 * OUT_C + 255) / 256, 256, 0, stream>>>(W3, Wt3, H1, 7);

    int mb = (n + 127) / 128;

    // Layer 1: t = bf16((x@W1)*dinv) ; agg -> out[:,0:256]
    gemm_mfma_kernel<<<dim3(mb, H2 / 128), 256, 0, stream>>>(x, IN_C, Wt1, IN_C, dinv, t, H2, n);
    agg_kernel<256><<<(n + 3) / 4, 256, 0, stream>>>(t, dinv, offs, csr, b1, out, 0, n);

    // Layer 2: t = bf16((h1@W2)*dinv) ; agg -> out[:,256:384]
    gemm_mfma_kernel<<<dim3(mb, H1 / 128), 256, 0, stream>>>(out, 512, Wt2, H2, dinv, t, H1, n);
    agg_kernel<128><<<(n + 3) / 4, 256, 0, stream>>>(t, dinv, offs, csr, b2, out, H2, n);

    // Layer 3: t = bf16((h2@W3)*dinv) ; agg -> out[:,384:512]
    gemm_mfma_kernel<<<dim3(mb, OUT_C / 128), 256, 0, stream>>>(out + H2, 512, Wt3, H1, dinv, t, OUT_C, n);
    agg_kernel<128><<<(n + 3) / 4, 256, 0, stream>>>(t, dinv, offs, csr, b3, out, H2 + H1, n);
}